// Round 6
// baseline (83.966 us; speedup 1.0000x reference)
//
#include <hip/hip_runtime.h>

// HistByProfMultiChannel: x (16,128,56,56) f32, hist_edges (128,10) f32,
// out (16,128,11) f32.
//
// R6: DIAGNOSTIC ROUND.
//  - Main dispatch <R=1>  : best-known direct-eval kernel -> d_out (~20.5us).
//  - Probe dispatch <R=5> : identical body, compute loop repeated 5x with an
//    asm value-barrier (prevents LICM/DCE; loads NOT repeated), -> d_ws.
//    Probe duration = T_fixed + 5*T_compute, main = T_fixed + T_compute.
//    If T_compute >= 5us the probe clears the 40us fillBuffer dispatches and
//    finally lands in rocprof's top-5 with VALUBusy/Occupancy/VGPR for this
//    exact body. Distinguishes "slow v_exp" vs "latency floor".

#define NE 10
#define NBINS 11
#define HW 3136
#define HW4 784
#define NCH 128

template<int R>
__global__ __launch_bounds__(256)
void hist_kernel(const float* __restrict__ x,
                 const float* __restrict__ edges,
                 float* __restrict__ out) {
    const int bc  = blockIdx.x;          // bt*NCH + c
    const int c   = bc & (NCH - 1);
    const int tid = threadIdx.x;

    const float LOG2E = 1.4426950408889634f;

    float e[NE];
    #pragma unroll
    for (int j = 0; j < NE; ++j) e[j] = edges[c * NE + j];

    // exp(-0.5*((v-mu)/sig)^2) = exp2(A*v^2 + B*v + C)
    float As[NE], Bs[NE], Cs[NE];
    {
        float mu  = e[0];
        float sig = (e[0] - e[1]) * (1.0f / 3.0f) + 1e-6f;
        float k   = -0.5f * LOG2E / (sig * sig);
        As[0] = k; Bs[0] = -2.0f * k * mu; Cs[0] = k * mu * mu;
    }
    #pragma unroll
    for (int j = 1; j < NE; ++j) {
        float mu  = (e[j - 1] + e[j]) * 0.5f;
        float sig = (e[j - 1] - e[j]) * (1.0f / 3.0f) + 1e-6f;
        float k   = -0.5f * LOG2E / (sig * sig);
        As[j] = k; Bs[j] = -2.0f * k * mu; Cs[j] = k * mu * mu;
    }
    const float sB = -20.0f * LOG2E;
    const float sC =  20.0f * LOG2E * e[NE - 1];

    // 16 pixels per thread (3 full float4 rounds + 16-lane tail, weight 0 pad)
    const float4* xp = (const float4*)(x + (size_t)bc * HW);
    float4 p0 = xp[tid];
    float4 p1 = xp[tid + 256];
    float4 p2 = xp[tid + 512];
    const bool tail = tid < (HW4 - 768);
    float4 p3 = make_float4(0.f, 0.f, 0.f, 0.f);
    if (tail) p3 = xp[768 + tid];
    const float wt = tail ? 1.0f : 0.0f;

    float vs[16] = {p0.x, p0.y, p0.z, p0.w, p1.x, p1.y, p1.z, p1.w,
                    p2.x, p2.y, p2.z, p2.w, p3.x, p3.y, p3.z, p3.w};
    float ws[16] = {1.f, 1.f, 1.f, 1.f, 1.f, 1.f, 1.f, 1.f,
                    1.f, 1.f, 1.f, 1.f, wt, wt, wt, wt};

    float acc[NBINS];
    #pragma unroll
    for (int j = 0; j < NBINS; ++j) acc[j] = 0.0f;

    #pragma unroll 1
    for (int r = 0; r < R; ++r) {
        #pragma unroll
        for (int k = 0; k < 16; ++k) {
            float v = vs[k];
            asm volatile("" : "+v"(v));   // defeat LICM across r-iterations
            float w  = ws[k];
            float v2 = v * v;
            #pragma unroll
            for (int j = 0; j < NE; ++j) {
                float arg = fmaf(As[j], v2, fmaf(Bs[j], v, Cs[j]));
                acc[j] = fmaf(__builtin_amdgcn_exp2f(arg), w, acc[j]);
            }
            float den = 1.0f + __builtin_amdgcn_exp2f(fmaf(sB, v, sC));
            acc[NE] = fmaf(__builtin_amdgcn_rcpf(den), w, acc[NE]);
        }
    }

    // Wave (64-lane) reduce each accumulator.
    #pragma unroll
    for (int j = 0; j < NBINS; ++j) {
        float a = acc[j];
        #pragma unroll
        for (int off = 32; off > 0; off >>= 1)
            a += __shfl_down(a, off, 64);
        acc[j] = a;
    }

    // Cross-wave reduce via LDS (4 waves x 11 bins).
    __shared__ float red[4][NBINS];
    const int wave = tid >> 6;
    const int lane = tid & 63;
    if (lane == 0) {
        #pragma unroll
        for (int j = 0; j < NBINS; ++j) red[wave][j] = acc[j];
    }
    __syncthreads();
    if (tid < NBINS) {
        float s = red[0][tid] + red[1][tid] + red[2][tid] + red[3][tid];
        out[(size_t)bc * NBINS + tid] = s;
    }
}

extern "C" void kernel_launch(void* const* d_in, const int* in_sizes, int n_in,
                              void* d_out, int out_size, void* d_ws, size_t ws_size,
                              hipStream_t stream) {
    const float* x     = (const float*)d_in[0];
    const float* edges = (const float*)d_in[1];
    float* out         = (float*)d_out;
    float* probe_out   = (float*)d_ws;   // scratch; never validated

    // Real result.
    hist_kernel<1><<<dim3(16 * NCH), dim3(256), 0, stream>>>(x, edges, out);
    // Diagnostic probe: 5x compute, same body, same occupancy. Results (5x
    // the true values) go to scratch. Deterministic, graph-capturable.
    hist_kernel<5><<<dim3(16 * NCH), dim3(256), 0, stream>>>(x, edges, probe_out);
}

// Round 7
// 19.803 us; speedup vs baseline: 4.2400x; 4.2400x over previous
//
#include <hip/hip_runtime.h>

// HistByProfMultiChannel: x (16,128,56,56) f32, hist_edges (128,10) f32,
// out (16,128,11) f32.
//
// R7: geometric-chain evaluation (uniform-edge fast path).
//   t_j(v) = A(v-mu_j)^2 (log2 space) has constant 2nd difference 2*A*D^2
//   when edges are uniformly spaced -> g_{j+1} = g_j * r, r *= rho.
//   Gaussian exp2 count per pixel: 4 (bin0 + checkpoints j=1,4,7) + 1 (r)
//   instead of 10. Checkpoints re-anchor the chain so FTZ underflow at a
//   far bin can't poison near bins (max chain span 2 => any bin with
//   g >= e^-26 has a normal-range anchor). v clamped at HC so r never
//   overflows to inf (beyond HC all Gaussians < e^-21).
//   Total trans/px: 7 (was 12). Probe R6 showed v_exp_f32 ~11cy issue-
//   blocking => predicted compute 12.9 -> ~9.6us.
//   Non-uniform edges: wave-uniform fallback to direct 12-trans eval.

#define NE 10
#define NBINS 11
#define HW 3136
#define HW4 784
#define NCH 128

__device__ __forceinline__ float rfl(float xv) {
    return __int_as_float(__builtin_amdgcn_readfirstlane(__float_as_int(xv)));
}

__global__ __launch_bounds__(256)
void hist_kernel(const float* __restrict__ x,
                 const float* __restrict__ edges,
                 float* __restrict__ out) {
    const int bc  = blockIdx.x;          // bt*NCH + c
    const int c   = bc & (NCH - 1);
    const int tid = threadIdx.x;

    const float LOG2E = 1.4426950408889634f;

    // Per-channel edges -> wave-uniform (SGPR).
    float e[NE];
    #pragma unroll
    for (int j = 0; j < NE; ++j) e[j] = rfl(edges[c * NE + j]);

    // ---- 16 pixels per thread, loaded up front ----
    const float4* xp = (const float4*)(x + (size_t)bc * HW);
    float4 p0 = xp[tid];
    float4 p1 = xp[tid + 256];
    float4 p2 = xp[tid + 512];
    float4 p3;
    if (tid < (HW4 - 768)) p3 = xp[768 + tid];
    else { p3.x = p3.y = p3.z = p3.w = -1e18f; }   // sentinel: all profiles -> 0

    float vs[16] = {p0.x, p0.y, p0.z, p0.w, p1.x, p1.y, p1.z, p1.w,
                    p2.x, p2.y, p2.z, p2.w, p3.x, p3.y, p3.z, p3.w};

    float acc[NBINS];
    #pragma unroll
    for (int j = 0; j < NBINS; ++j) acc[j] = 0.0f;

    // Uniform-spacing check (wave-uniform result).
    const float D = e[1] - e[0];
    bool uniform = (D > 1e-6f);
    #pragma unroll
    for (int j = 1; j < NE - 1; ++j)
        uniform = uniform && (fabsf((e[j + 1] - e[j]) - D) <= 1e-4f * fabsf(D));

    // Sigmoid constants (both paths): 1/(1+exp2(sB*v+sC))
    const float sB = rfl(-20.0f * LOG2E);
    const float sC = rfl(20.0f * LOG2E * e[NE - 1]);

    if (uniform) {
        // sig identical for ALL bins (incl. bin0): (e[j-1]-e[j])/3 + 1e-6
        const float sg  = -D * (1.0f / 3.0f) + 1e-6f;
        const float A   = rfl(-0.5f * LOG2E / (sg * sg));   // < 0
        // mu: bin0 = e0; interior mu_j = e0 + (j - 0.5)*D, j=1..9
        const float mu1 = e[0] + 0.5f * D;
        const float mu4 = e[0] + 3.5f * D;
        const float mu7 = e[0] + 6.5f * D;
        const float B0 = rfl(-2.0f * A * e[0]), C0 = rfl(A * e[0] * e[0]);
        const float B1 = rfl(-2.0f * A * mu1),  C1 = rfl(A * mu1 * mu1);
        const float B4 = rfl(-2.0f * A * mu4),  C4 = rfl(A * mu4 * mu4);
        const float B7 = rfl(-2.0f * A * mu7),  C7 = rfl(A * mu7 * mu7);
        // r(v) = exp2(dB*v + dC) = g2/g1 ; rho = r_{j+1}/r_j (v-independent)
        const float dB  = rfl(-2.0f * A * D);               // > 0
        const float dC  = rfl(A * D * (mu1 + mu1 + D));     // A*D*(mu1+mu2)
        const float rho = rfl(__builtin_amdgcn_exp2f(2.0f * A * D * D));
        // Clamp so dB*v + dC <= 126 (r finite). Beyond HC every Gaussian
        // is < e^-21 (distance > 4.4 sigma + 2 bins).
        const float HC  = rfl((126.0f - dC) / dB);

        #pragma unroll
        for (int k = 0; k < 16; ++k) {
            float v  = vs[k];
            float vg = fminf(v, HC);
            float v2 = vg * vg;
            float t0 = fmaf(A, v2, fmaf(B0, vg, C0));
            float t1 = fmaf(A, v2, fmaf(B1, vg, C1));
            float t4 = fmaf(A, v2, fmaf(B4, vg, C4));
            float t7 = fmaf(A, v2, fmaf(B7, vg, C7));
            float r  = __builtin_amdgcn_exp2f(fmaf(dB, vg, dC));
            acc[0] += __builtin_amdgcn_exp2f(t0);
            float g = __builtin_amdgcn_exp2f(t1);
            acc[1] += g;
            g *= r; r *= rho; acc[2] += g;
            g *= r; r *= rho; acc[3] += g;
            g  = __builtin_amdgcn_exp2f(t4); r *= rho; acc[4] += g;
            g *= r; r *= rho; acc[5] += g;
            g *= r; r *= rho; acc[6] += g;
            g  = __builtin_amdgcn_exp2f(t7); r *= rho; acc[7] += g;
            g *= r; r *= rho; acc[8] += g;
            g *= r;           acc[9] += g;
            float den = 1.0f + __builtin_amdgcn_exp2f(fmaf(sB, v, sC));
            acc[10] += __builtin_amdgcn_rcpf(den);
        }
    } else {
        // General path: direct per-bin quadratic exp2 (exact R2 body).
        float As[NE], Bs[NE], Cs[NE];
        {
            float mu  = e[0];
            float sg  = (e[0] - e[1]) * (1.0f / 3.0f) + 1e-6f;
            float kk  = -0.5f * LOG2E / (sg * sg);
            As[0] = rfl(kk); Bs[0] = rfl(-2.0f * kk * mu); Cs[0] = rfl(kk * mu * mu);
        }
        #pragma unroll
        for (int j = 1; j < NE; ++j) {
            float mu  = (e[j - 1] + e[j]) * 0.5f;
            float sg  = (e[j - 1] - e[j]) * (1.0f / 3.0f) + 1e-6f;
            float kk  = -0.5f * LOG2E / (sg * sg);
            As[j] = rfl(kk); Bs[j] = rfl(-2.0f * kk * mu); Cs[j] = rfl(kk * mu * mu);
        }
        #pragma unroll
        for (int k = 0; k < 16; ++k) {
            float v  = vs[k];
            float v2 = v * v;
            #pragma unroll
            for (int j = 0; j < NE; ++j) {
                float arg = fmaf(As[j], v2, fmaf(Bs[j], v, Cs[j]));
                acc[j] += __builtin_amdgcn_exp2f(arg);
            }
            float den = 1.0f + __builtin_amdgcn_exp2f(fmaf(sB, v, sC));
            acc[10] += __builtin_amdgcn_rcpf(den);
        }
    }

    // Wave (64-lane) reduce each accumulator.
    #pragma unroll
    for (int j = 0; j < NBINS; ++j) {
        float a = acc[j];
        #pragma unroll
        for (int off = 32; off > 0; off >>= 1)
            a += __shfl_down(a, off, 64);
        acc[j] = a;
    }

    // Cross-wave reduce via LDS (4 waves x 11 bins).
    __shared__ float red[4][NBINS];
    const int wave = tid >> 6;
    const int lane = tid & 63;
    if (lane == 0) {
        #pragma unroll
        for (int j = 0; j < NBINS; ++j) red[wave][j] = acc[j];
    }
    __syncthreads();
    if (tid < NBINS) {
        float s = red[0][tid] + red[1][tid] + red[2][tid] + red[3][tid];
        out[(size_t)bc * NBINS + tid] = s;
    }
}

extern "C" void kernel_launch(void* const* d_in, const int* in_sizes, int n_in,
                              void* d_out, int out_size, void* d_ws, size_t ws_size,
                              hipStream_t stream) {
    const float* x     = (const float*)d_in[0];
    const float* edges = (const float*)d_in[1];
    float* out         = (float*)d_out;
    hist_kernel<<<dim3(16 * NCH), dim3(256), 0, stream>>>(x, edges, out);
}